// Round 5
// baseline (407.810 us; speedup 1.0000x reference)
//
#include <hip/hip_runtime.h>

typedef unsigned short u16;
typedef __attribute__((ext_vector_type(8))) short bfrag;  // 8 bf16 (4 VGPRs)
typedef __attribute__((ext_vector_type(4))) short sfrag;  // 4 bf16 (2 VGPRs)
typedef __attribute__((ext_vector_type(4))) float ffrag;  // 4 fp32

// B=256, L=200, D=256, H=16, Dh=16, M=51200
// Head-major slice: [B,H,L,16], slice stride 3200 u16, b-stride 51200 u16.

__device__ __forceinline__ float bf2f(u16 u) {
    union { float f; unsigned int i; } c; c.i = ((unsigned int)u) << 16; return c.f;
}
__device__ __forceinline__ u16 f2bf(float f) {
    union { float f; unsigned int i; } c; c.f = f;
    unsigned int r = c.i + 0x7FFFu + ((c.i >> 16) & 1u);  // RNE
    return (u16)(r >> 16);
}
__device__ __forceinline__ ffrag mfma16(bfrag a, bfrag b, ffrag c) {
    return __builtin_amdgcn_mfma_f32_16x16x32_bf16(a, b, c, 0, 0, 0);
}
__device__ __forceinline__ ffrag mfma16k16(sfrag a, sfrag b, ffrag c) {
    return __builtin_amdgcn_mfma_f32_16x16x16bf16_1k(a, b, c, 0, 0, 0);
}

// ---------------------------------------------------------------------------
// LDS-tiled transpose+cast: W[k][n] f32 -> Wt[n][k] bf16, 4 matrices.
// ---------------------------------------------------------------------------
__global__ __launch_bounds__(256) void wtrans_k(
    const float* __restrict__ W0, const float* __restrict__ W1,
    const float* __restrict__ W2, const float* __restrict__ W3,
    u16* __restrict__ Wt)
{
    __shared__ u16 t_s[64][72];
    const int mat = blockIdx.z;
    const float* W = (mat == 0) ? W0 : (mat == 1) ? W1 : (mat == 2) ? W2 : W3;
    const int k0 = blockIdx.x * 64, n0 = blockIdx.y * 64;
    const int r = threadIdx.x >> 2, cq = threadIdx.x & 3;

    const float* src = W + (size_t)(k0 + r) * 256 + n0 + cq * 16;
#pragma unroll
    for (int j = 0; j < 16; j += 4) {
        float4 f = *(const float4*)(src + j);
        t_s[cq * 16 + j + 0][r] = f2bf(f.x);
        t_s[cq * 16 + j + 1][r] = f2bf(f.y);
        t_s[cq * 16 + j + 2][r] = f2bf(f.z);
        t_s[cq * 16 + j + 3][r] = f2bf(f.w);
    }
    __syncthreads();
    u16* dst = Wt + ((size_t)mat * 256 + n0 + r) * 256 + k0 + cq * 16;
    *(bfrag*)(dst)     = *(const bfrag*)&t_s[r][cq * 16];
    *(bfrag*)(dst + 8) = *(const bfrag*)&t_s[r][cq * 16 + 8];
}

// ---------------------------------------------------------------------------
// GEMM: C[M,256or768] = A[M,256] @ Wt^T + bias.  (unchanged from round 4)
// ---------------------------------------------------------------------------
template<bool QKV>
__global__ __launch_bounds__(256) void gemm_k(
    const void* __restrict__ Avp, const u16* __restrict__ Wtp,
    const float* __restrict__ b0, const float* __restrict__ b1,
    const float* __restrict__ b2,
    u16* __restrict__ o0, u16* __restrict__ o1, u16* __restrict__ o2)
{
    const int m0 = blockIdx.x * 128;
    const int n0g = blockIdx.y * 128;
    const int tid = threadIdx.x;
    const int wave = tid >> 6, lane = tid & 63;
    const int quad = lane >> 4, l16 = lane & 15;
    const int wm = wave >> 1, wn = wave & 1;

    __shared__ u16 a_s[4][128][8];
    __shared__ u16 b_s[4][128][8];

    ffrag zf = {0.f, 0.f, 0.f, 0.f};
    ffrag acc[4][4];
#pragma unroll
    for (int mi = 0; mi < 4; mi++)
#pragma unroll
        for (int ni = 0; ni < 4; ni++) acc[mi][ni] = zf;

    const int sr = tid >> 2;
    const int sc = tid & 3;
    const float* Af = (const float*)Avp;
    const u16*   Ab = (const u16*)Avp;
    const u16* Wp = Wtp + (size_t)(n0g + sr) * 256 + sc * 8;

    int r0 = m0 + sr, r1 = r0 + 64;
    unsigned bA0 = (unsigned)r0 / 200u, bA1 = (unsigned)r1 / 200u;
    size_t base0 = (size_t)bA0 * 51200 + (r0 - bA0 * 200) * 16;
    size_t base1 = (size_t)bA1 * 51200 + (r1 - bA1 * 200) * 16;

    for (int kk = 0; kk < 256; kk += 32) {
        __syncthreads();
        if constexpr (QKV) {
            const float* p0 = Af + (size_t)r0 * 256 + sc * 8 + kk;
            const float* p1 = Af + (size_t)r1 * 256 + sc * 8 + kk;
            float4 f0 = *(const float4*)p0, f1 = *(const float4*)(p0 + 4);
            float4 g0 = *(const float4*)p1, g1 = *(const float4*)(p1 + 4);
            bfrag v0, v1;
            v0[0] = (short)f2bf(f0.x); v0[1] = (short)f2bf(f0.y);
            v0[2] = (short)f2bf(f0.z); v0[3] = (short)f2bf(f0.w);
            v0[4] = (short)f2bf(f1.x); v0[5] = (short)f2bf(f1.y);
            v0[6] = (short)f2bf(f1.z); v0[7] = (short)f2bf(f1.w);
            v1[0] = (short)f2bf(g0.x); v1[1] = (short)f2bf(g0.y);
            v1[2] = (short)f2bf(g0.z); v1[3] = (short)f2bf(g0.w);
            v1[4] = (short)f2bf(g1.x); v1[5] = (short)f2bf(g1.y);
            v1[6] = (short)f2bf(g1.z); v1[7] = (short)f2bf(g1.w);
            *(bfrag*)&a_s[sc][sr        ^ (sc << 2)][0] = v0;
            *(bfrag*)&a_s[sc][(sr + 64) ^ (sc << 2)][0] = v1;
        } else {
            int c = kk + sc * 8;
            size_t hofs = (size_t)(c >> 4) * 3200 + (c & 8);
            *(bfrag*)&a_s[sc][sr        ^ (sc << 2)][0] = *(const bfrag*)(Ab + base0 + hofs);
            *(bfrag*)&a_s[sc][(sr + 64) ^ (sc << 2)][0] = *(const bfrag*)(Ab + base1 + hofs);
        }
        *(bfrag*)&b_s[sc][sr        ^ (sc << 2)][0] = *(const bfrag*)(Wp + kk);
        *(bfrag*)&b_s[sc][(sr + 64) ^ (sc << 2)][0] = *(const bfrag*)(Wp + (size_t)64 * 256 + kk);
        __syncthreads();

        bfrag af[4], bfr[4];
#pragma unroll
        for (int mi = 0; mi < 4; mi++) {
            int m = wm * 64 + mi * 16 + l16;
            af[mi] = *(const bfrag*)&a_s[quad][m ^ (quad << 2)][0];
        }
#pragma unroll
        for (int ni = 0; ni < 4; ni++) {
            int n = wn * 64 + ni * 16 + l16;
            bfr[ni] = *(const bfrag*)&b_s[quad][n ^ (quad << 2)][0];
        }
#pragma unroll
        for (int mi = 0; mi < 4; mi++)
#pragma unroll
            for (int ni = 0; ni < 4; ni++)
                acc[mi][ni] = mfma16(af[mi], bfr[ni], acc[mi][ni]);
    }

    if constexpr (QKV) {
        const float* bias = (blockIdx.y < 2) ? b0 : (blockIdx.y < 4) ? b1 : b2;
        u16* dst = (blockIdx.y < 2) ? o0 : (blockIdx.y < 4) ? o1 : o2;
#pragma unroll
        for (int ni = 0; ni < 4; ni++) {
            int nloc = (blockIdx.y & 1) * 128 + wn * 64 + ni * 16 + l16;
            float bb = bias[nloc];
            size_t hbase = (size_t)(nloc >> 4) * 3200 + (nloc & 15);
#pragma unroll
            for (int mi = 0; mi < 4; mi++) {
                int rowb = m0 + wm * 64 + mi * 16 + quad * 4;
#pragma unroll
                for (int r = 0; r < 4; r++) {
                    unsigned row = rowb + r;
                    unsigned bb_ = row / 200u, ll = row - bb_ * 200u;
                    dst[(size_t)bb_ * 51200 + hbase + ll * 16] = f2bf(acc[mi][ni][r] + bb);
                }
            }
        }
    } else {
#pragma unroll
        for (int ni = 0; ni < 4; ni++) {
            int col = n0g + wn * 64 + ni * 16 + l16;
            float bb = b0[col];
#pragma unroll
            for (int mi = 0; mi < 4; mi++) {
                int rowb = m0 + wm * 64 + mi * 16 + quad * 4;
#pragma unroll
                for (int r = 0; r < 4; r++)
                    o0[(size_t)(rowb + r) * 256 + col] = f2bf(acc[mi][ni][r] + bb);
            }
        }
    }
}

// ---------------------------------------------------------------------------
// MHA per (b,h). grid 4096, block 256 (4 waves).
// S^T = K·Q^T via mfma_16x16x16 (D[row=quad*4+r][col=l16] = S[q=l16][k=...]),
// so P is ALREADY in the A-operand layout of the K=16 PV MFMA: no LDS
// round-trip, no swizzle. Softmax = per-lane over 52 + shfl_xor(16,32).
// V staged transposed in LDS (B-frag = one ds_read_b64). ctx in-place over Q.
// ---------------------------------------------------------------------------
__global__ __launch_bounds__(256, 4) void attn_k(
    u16* __restrict__ Q, const u16* __restrict__ K,
    const u16* __restrict__ V, const int* __restrict__ msk)
{
    const int blk = blockIdx.x;            // b*16+h
    const int b = blk >> 4;
    const int tid = threadIdx.x;
    const int wave = tid >> 6, lane = tid & 63;
    const int quad = lane >> 4, l16 = lane & 15;
    const size_t sbase = (size_t)blk * 3200;

    __shared__ u16 vt_s[16][228];              // V^T [dh][k], pitch 228 (8B-mult, odd b64 stride)
    __shared__ __align__(16) float am_s[224];  // additive key mask (pad -1e30)

    for (int i = tid; i < 224; i += 256)
        am_s[i] = (i < 200) ? (msk[b * 200 + i] ? 0.f : -10000.f) : -1e30f;
    for (int i = tid; i < 16 * 28; i += 256)   // zero V^T pad cols 200..227
        vt_s[i / 28][200 + i % 28] = 0;
    for (int i = tid; i < 400; i += 256) {     // stage V^T
        int l = i >> 1, hf = i & 1;
        bfrag v = *(const bfrag*)(V + sbase + l * 16 + hf * 8);
#pragma unroll
        for (int j = 0; j < 8; j++) vt_s[hf * 8 + j][l] = (u16)v[j];
    }
    __syncthreads();

    for (int t = wave; t < 13; t += 4) {
        int qb = t * 16;
        int lq = qb + l16; if (lq > 199) lq = 199;     // clamp (writes guarded)
        // Q B-frag: B[c=d=quad*4+j][n=q=l16]
        sfrag qf = *(const sfrag*)(Q + sbase + lq * 16 + quad * 4);

        // ---- S^T tiles: lane gets S[q=l16][k=kt*16+quad*4+r], r=0..3
        float s[13][4];
#pragma unroll
        for (int kt = 0; kt < 13; kt++) {
            int lk = kt * 16 + l16; if (lk > 199) lk = 199;
            sfrag kf = *(const sfrag*)(K + sbase + lk * 16 + quad * 4);
            ffrag c = {0.f, 0.f, 0.f, 0.f};
            c = mfma16k16(kf, qf, c);                   // D = K·Q^T tile
            ffrag am4 = *(const ffrag*)&am_s[kt * 16 + quad * 4];
#pragma unroll
            for (int r = 0; r < 4; r++) s[kt][r] = c[r] * 0.25f + am4[r];
        }
        // ---- softmax over k: per-lane 52 values, then quads (xor 16,32)
        float mx = s[0][0];
#pragma unroll
        for (int kt = 0; kt < 13; kt++)
#pragma unroll
            for (int r = 0; r < 4; r++) mx = fmaxf(mx, s[kt][r]);
        mx = fmaxf(mx, __shfl_xor(mx, 16, 64));
        mx = fmaxf(mx, __shfl_xor(mx, 32, 64));
        float sm = 0.f;
#pragma unroll
        for (int kt = 0; kt < 13; kt++)
#pragma unroll
            for (int r = 0; r < 4; r++) {
                float p = __expf(s[kt][r] - mx);
                s[kt][r] = p; sm += p;
            }
        sm += __shfl_xor(sm, 16, 64);
        sm += __shfl_xor(sm, 32, 64);
        float rs = 1.0f / sm;
        // ---- P already in A-layout; normalize, cvt to bf16 frags in-reg
        sfrag pf[13];
#pragma unroll
        for (int kt = 0; kt < 13; kt++)
#pragma unroll
            for (int r = 0; r < 4; r++)
                pf[kt][r] = (short)f2bf(s[kt][r] * rs);
        // ---- PV: O[q][d] = sum_k P[q][k] V[k][d]
        ffrag o = {0.f, 0.f, 0.f, 0.f};
#pragma unroll
        for (int kt = 0; kt < 13; kt++) {
            sfrag bv = *(const sfrag*)&vt_s[l16][kt * 16 + quad * 4];
            o = mfma16k16(pf[kt], bv, o);
        }
        // D row=quad*4+r = q-local, col=l16 = d
#pragma unroll
        for (int r = 0; r < 4; r++) {
            int l = qb + quad * 4 + r;
            if (l < 200)
                Q[sbase + l * 16 + l16] = f2bf(o[r]);  // ctx in-place
        }
    }
}

// ---------------------------------------------------------------------------
// Query pooling per batch. grid 256, block 256. f32 out.
// ---------------------------------------------------------------------------
__global__ __launch_bounds__(256) void pool_k(
    const u16* __restrict__ NO, const int* __restrict__ msk,
    const float* __restrict__ qn, float* __restrict__ out)
{
    const int b = blockIdx.x;
    const int tid = threadIdx.x;
    __shared__ float q_sh[256];
    __shared__ float p_sh[256];
    __shared__ float redm[4], reds[4];

    q_sh[tid] = qn[tid];
    __syncthreads();

    float s = -1e30f;
    if (tid < 200) {
        const u16* row = NO + (size_t)(b * 200 + tid) * 256;
        float acc = 0.f;
        for (int d0 = 0; d0 < 256; d0 += 8) {
            bfrag v = *(const bfrag*)(row + d0);
#pragma unroll
            for (int j = 0; j < 8; j++) acc += bf2f((u16)v[j]) * q_sh[d0 + j];
        }
        s = acc * 0.0625f;
        if (msk[b * 200 + tid] == 0) s = -1e9f;
    }
    float m = s;
#pragma unroll
    for (int d = 1; d < 64; d <<= 1) m = fmaxf(m, __shfl_xor(m, d, 64));
    if ((tid & 63) == 0) redm[tid >> 6] = m;
    __syncthreads();
    m = fmaxf(fmaxf(redm[0], redm[1]), fmaxf(redm[2], redm[3]));
    float e = __expf(s - m);
    float sum = e;
#pragma unroll
    for (int d = 1; d < 64; d <<= 1) sum += __shfl_xor(sum, d, 64);
    if ((tid & 63) == 0) reds[tid >> 6] = sum;
    __syncthreads();
    sum = reds[0] + reds[1] + reds[2] + reds[3];
    p_sh[tid] = e / sum;
    __syncthreads();

    float acc = 0.f;
    for (int l = 0; l < 200; l++)
        acc += p_sh[l] * bf2f(NO[(size_t)(b * 200 + l) * 256 + tid]);
    out[(size_t)b * 256 + tid] = acc;
}

// ---------------------------------------------------------------------------
extern "C" void kernel_launch(void* const* d_in, const int* in_sizes, int n_in,
                              void* d_out, int out_size, void* d_ws, size_t ws_size,
                              hipStream_t stream) {
    const float* X   = (const float*)d_in[0];
    const int*   msk = (const int*)d_in[1];
    const float* Wq  = (const float*)d_in[2];
    const float* bq  = (const float*)d_in[3];
    const float* Wk  = (const float*)d_in[4];
    const float* bk  = (const float*)d_in[5];
    const float* Wv  = (const float*)d_in[6];
    const float* bv  = (const float*)d_in[7];
    const float* Wo  = (const float*)d_in[8];
    const float* bo  = (const float*)d_in[9];
    const float* qn  = (const float*)d_in[10];
    float* out = (float*)d_out;

    // ws layout (79,167,488 B):
    //   qbuf: Q head-major -> ctx in-place     26,214,400
    //   kbuf: K head-major -> news_out l-major 26,214,400
    //   vbuf: V head-major                     26,214,400
    //   wt:   [1024][256] bf16 (Wq,Wk,Wv,Wo)^T    524,288
    char* ws = (char*)d_ws;
    u16* qbuf = (u16*)(ws);
    u16* kbuf = (u16*)(ws + 26214400);
    u16* vbuf = (u16*)(ws + 52428800);
    u16* wt   = (u16*)(ws + 78643200);

    wtrans_k<<<dim3(4, 4, 4), 256, 0, stream>>>(Wq, Wk, Wv, Wo, wt);

    gemm_k<true><<<dim3(400, 6), 256, 0, stream>>>(
        X, wt, bq, bk, bv, qbuf, kbuf, vbuf);

    attn_k<<<4096, 256, 0, stream>>>(qbuf, kbuf, vbuf, msk);

    gemm_k<false><<<dim3(400, 2), 256, 0, stream>>>(
        qbuf, wt + 196608, bo, nullptr, nullptr, kbuf, nullptr, nullptr);

    pool_k<<<256, 256, 0, stream>>>(kbuf, msk, qn, out);
}

// Round 6
// 270.029 us; speedup vs baseline: 1.5102x; 1.5102x over previous
//
#include <hip/hip_runtime.h>

typedef unsigned short u16;
typedef __attribute__((ext_vector_type(8))) short bfrag;  // 8 bf16 (4 VGPRs)
typedef __attribute__((ext_vector_type(4))) short sfrag;  // 4 bf16 (2 VGPRs)
typedef __attribute__((ext_vector_type(4))) float ffrag;  // 4 fp32

// B=256, L=200, D=256, H=16, Dh=16, M=51200
// Head-major slice: [B,H,L,16], slice stride 3200 u16, b-stride 51200 u16.

__device__ __forceinline__ float bf2f(u16 u) {
    union { float f; unsigned int i; } c; c.i = ((unsigned int)u) << 16; return c.f;
}
__device__ __forceinline__ u16 f2bf(float f) {
    union { float f; unsigned int i; } c; c.f = f;
    unsigned int r = c.i + 0x7FFFu + ((c.i >> 16) & 1u);  // RNE
    return (u16)(r >> 16);
}
__device__ __forceinline__ ffrag mfma16(bfrag a, bfrag b, ffrag c) {
    return __builtin_amdgcn_mfma_f32_16x16x32_bf16(a, b, c, 0, 0, 0);
}
__device__ __forceinline__ ffrag mfma16k16(sfrag a, sfrag b, ffrag c) {
    return __builtin_amdgcn_mfma_f32_16x16x16bf16_1k(a, b, c, 0, 0, 0);
}

// ---------------------------------------------------------------------------
// LDS-tiled transpose+cast: W[k][n] f32 -> Wt[n][k] bf16, 4 matrices.
// ---------------------------------------------------------------------------
__global__ __launch_bounds__(256) void wtrans_k(
    const float* __restrict__ W0, const float* __restrict__ W1,
    const float* __restrict__ W2, const float* __restrict__ W3,
    u16* __restrict__ Wt)
{
    __shared__ u16 t_s[64][72];
    const int mat = blockIdx.z;
    const float* W = (mat == 0) ? W0 : (mat == 1) ? W1 : (mat == 2) ? W2 : W3;
    const int k0 = blockIdx.x * 64, n0 = blockIdx.y * 64;
    const int r = threadIdx.x >> 2, cq = threadIdx.x & 3;

    const float* src = W + (size_t)(k0 + r) * 256 + n0 + cq * 16;
#pragma unroll
    for (int j = 0; j < 16; j += 4) {
        float4 f = *(const float4*)(src + j);
        t_s[cq * 16 + j + 0][r] = f2bf(f.x);
        t_s[cq * 16 + j + 1][r] = f2bf(f.y);
        t_s[cq * 16 + j + 2][r] = f2bf(f.z);
        t_s[cq * 16 + j + 3][r] = f2bf(f.w);
    }
    __syncthreads();
    u16* dst = Wt + ((size_t)mat * 256 + n0 + r) * 256 + k0 + cq * 16;
    *(bfrag*)(dst)     = *(const bfrag*)&t_s[r][cq * 16];
    *(bfrag*)(dst + 8) = *(const bfrag*)&t_s[r][cq * 16 + 8];
}

// ---------------------------------------------------------------------------
// GEMM: C[M,256or768] = A[M,256] @ Wt^T + bias.  (unchanged)
// ---------------------------------------------------------------------------
template<bool QKV>
__global__ __launch_bounds__(256) void gemm_k(
    const void* __restrict__ Avp, const u16* __restrict__ Wtp,
    const float* __restrict__ b0, const float* __restrict__ b1,
    const float* __restrict__ b2,
    u16* __restrict__ o0, u16* __restrict__ o1, u16* __restrict__ o2)
{
    const int m0 = blockIdx.x * 128;
    const int n0g = blockIdx.y * 128;
    const int tid = threadIdx.x;
    const int wave = tid >> 6, lane = tid & 63;
    const int quad = lane >> 4, l16 = lane & 15;
    const int wm = wave >> 1, wn = wave & 1;

    __shared__ u16 a_s[4][128][8];
    __shared__ u16 b_s[4][128][8];

    ffrag zf = {0.f, 0.f, 0.f, 0.f};
    ffrag acc[4][4];
#pragma unroll
    for (int mi = 0; mi < 4; mi++)
#pragma unroll
        for (int ni = 0; ni < 4; ni++) acc[mi][ni] = zf;

    const int sr = tid >> 2;
    const int sc = tid & 3;
    const float* Af = (const float*)Avp;
    const u16*   Ab = (const u16*)Avp;
    const u16* Wp = Wtp + (size_t)(n0g + sr) * 256 + sc * 8;

    int r0 = m0 + sr, r1 = r0 + 64;
    unsigned bA0 = (unsigned)r0 / 200u, bA1 = (unsigned)r1 / 200u;
    size_t base0 = (size_t)bA0 * 51200 + (r0 - bA0 * 200) * 16;
    size_t base1 = (size_t)bA1 * 51200 + (r1 - bA1 * 200) * 16;

    for (int kk = 0; kk < 256; kk += 32) {
        __syncthreads();
        if constexpr (QKV) {
            const float* p0 = Af + (size_t)r0 * 256 + sc * 8 + kk;
            const float* p1 = Af + (size_t)r1 * 256 + sc * 8 + kk;
            float4 f0 = *(const float4*)p0, f1 = *(const float4*)(p0 + 4);
            float4 g0 = *(const float4*)p1, g1 = *(const float4*)(p1 + 4);
            bfrag v0, v1;
            v0[0] = (short)f2bf(f0.x); v0[1] = (short)f2bf(f0.y);
            v0[2] = (short)f2bf(f0.z); v0[3] = (short)f2bf(f0.w);
            v0[4] = (short)f2bf(f1.x); v0[5] = (short)f2bf(f1.y);
            v0[6] = (short)f2bf(f1.z); v0[7] = (short)f2bf(f1.w);
            v1[0] = (short)f2bf(g0.x); v1[1] = (short)f2bf(g0.y);
            v1[2] = (short)f2bf(g0.z); v1[3] = (short)f2bf(g0.w);
            v1[4] = (short)f2bf(g1.x); v1[5] = (short)f2bf(g1.y);
            v1[6] = (short)f2bf(g1.z); v1[7] = (short)f2bf(g1.w);
            *(bfrag*)&a_s[sc][sr        ^ (sc << 2)][0] = v0;
            *(bfrag*)&a_s[sc][(sr + 64) ^ (sc << 2)][0] = v1;
        } else {
            int c = kk + sc * 8;
            size_t hofs = (size_t)(c >> 4) * 3200 + (c & 8);
            *(bfrag*)&a_s[sc][sr        ^ (sc << 2)][0] = *(const bfrag*)(Ab + base0 + hofs);
            *(bfrag*)&a_s[sc][(sr + 64) ^ (sc << 2)][0] = *(const bfrag*)(Ab + base1 + hofs);
        }
        *(bfrag*)&b_s[sc][sr        ^ (sc << 2)][0] = *(const bfrag*)(Wp + kk);
        *(bfrag*)&b_s[sc][(sr + 64) ^ (sc << 2)][0] = *(const bfrag*)(Wp + (size_t)64 * 256 + kk);
        __syncthreads();

        bfrag af[4], bfr[4];
#pragma unroll
        for (int mi = 0; mi < 4; mi++) {
            int m = wm * 64 + mi * 16 + l16;
            af[mi] = *(const bfrag*)&a_s[quad][m ^ (quad << 2)][0];
        }
#pragma unroll
        for (int ni = 0; ni < 4; ni++) {
            int n = wn * 64 + ni * 16 + l16;
            bfr[ni] = *(const bfrag*)&b_s[quad][n ^ (quad << 2)][0];
        }
#pragma unroll
        for (int mi = 0; mi < 4; mi++)
#pragma unroll
            for (int ni = 0; ni < 4; ni++)
                acc[mi][ni] = mfma16(af[mi], bfr[ni], acc[mi][ni]);
    }

    if constexpr (QKV) {
        const float* bias = (blockIdx.y < 2) ? b0 : (blockIdx.y < 4) ? b1 : b2;
        u16* dst = (blockIdx.y < 2) ? o0 : (blockIdx.y < 4) ? o1 : o2;
#pragma unroll
        for (int ni = 0; ni < 4; ni++) {
            int nloc = (blockIdx.y & 1) * 128 + wn * 64 + ni * 16 + l16;
            float bb = bias[nloc];
            size_t hbase = (size_t)(nloc >> 4) * 3200 + (nloc & 15);
#pragma unroll
            for (int mi = 0; mi < 4; mi++) {
                int rowb = m0 + wm * 64 + mi * 16 + quad * 4;
#pragma unroll
                for (int r = 0; r < 4; r++) {
                    unsigned row = rowb + r;
                    unsigned bb_ = row / 200u, ll = row - bb_ * 200u;
                    dst[(size_t)bb_ * 51200 + hbase + ll * 16] = f2bf(acc[mi][ni][r] + bb);
                }
            }
        }
    } else {
#pragma unroll
        for (int ni = 0; ni < 4; ni++) {
            int col = n0g + wn * 64 + ni * 16 + l16;
            float bb = b0[col];
#pragma unroll
            for (int mi = 0; mi < 4; mi++) {
                int rowb = m0 + wm * 64 + mi * 16 + quad * 4;
#pragma unroll
                for (int r = 0; r < 4; r++)
                    o0[(size_t)(rowb + r) * 256 + col] = f2bf(acc[mi][ni][r] + bb);
            }
        }
    }
}

// ---------------------------------------------------------------------------
// MHA per (b,h). grid 4096, block 256 (4 waves).
// S^T = K·Q^T via mfma_16x16x16 (D[row=quad*4+r][col=l16] = S[q=l16][k=...]),
// so P is ALREADY in the A-operand layout of the K=16 PV MFMA.
// pf built per-iteration inside the PV loop (NOT an array) — keeps peak
// live regs ≈ 80; NO min-waves clamp in launch_bounds (r5's (256,4) forced
// VGPR<=64 and spilled s[13][4] to scratch: FETCH 445 MB / WRITE 302 MB).
// ---------------------------------------------------------------------------
__global__ __launch_bounds__(256) void attn_k(
    u16* __restrict__ Q, const u16* __restrict__ K,
    const u16* __restrict__ V, const int* __restrict__ msk)
{
    const int blk = blockIdx.x;            // b*16+h
    const int b = blk >> 4;
    const int tid = threadIdx.x;
    const int wave = tid >> 6, lane = tid & 63;
    const int quad = lane >> 4, l16 = lane & 15;
    const size_t sbase = (size_t)blk * 3200;

    __shared__ u16 vt_s[16][228];              // V^T [dh][k], pitch 228
    __shared__ __align__(16) float am_s[224];  // additive key mask (pad -1e30)

    for (int i = tid; i < 224; i += 256)
        am_s[i] = (i < 200) ? (msk[b * 200 + i] ? 0.f : -10000.f) : -1e30f;
    for (int i = tid; i < 16 * 28; i += 256)   // zero V^T pad cols 200..227
        vt_s[i / 28][200 + i % 28] = 0;
    for (int i = tid; i < 400; i += 256) {     // stage V^T
        int l = i >> 1, hf = i & 1;
        bfrag v = *(const bfrag*)(V + sbase + l * 16 + hf * 8);
#pragma unroll
        for (int j = 0; j < 8; j++) vt_s[hf * 8 + j][l] = (u16)v[j];
    }
    __syncthreads();

    for (int t = wave; t < 13; t += 4) {
        int qb = t * 16;
        int lq = qb + l16; if (lq > 199) lq = 199;     // clamp (writes guarded)
        sfrag qf = *(const sfrag*)(Q + sbase + lq * 16 + quad * 4);

        // ---- S^T tiles: lane gets S[q=l16][k=kt*16+quad*4+r], r=0..3
        float s[13][4];
#pragma unroll
        for (int kt = 0; kt < 13; kt++) {
            int lk = kt * 16 + l16; if (lk > 199) lk = 199;
            sfrag kf = *(const sfrag*)(K + sbase + lk * 16 + quad * 4);
            ffrag c = {0.f, 0.f, 0.f, 0.f};
            c = mfma16k16(kf, qf, c);                   // D = K·Q^T tile
            ffrag am4 = *(const ffrag*)&am_s[kt * 16 + quad * 4];
#pragma unroll
            for (int r = 0; r < 4; r++) s[kt][r] = c[r] * 0.25f + am4[r];
        }
        // ---- softmax over k: per-lane 52 values, then quads (xor 16,32)
        float mx = s[0][0];
#pragma unroll
        for (int kt = 0; kt < 13; kt++)
#pragma unroll
            for (int r = 0; r < 4; r++) mx = fmaxf(mx, s[kt][r]);
        mx = fmaxf(mx, __shfl_xor(mx, 16, 64));
        mx = fmaxf(mx, __shfl_xor(mx, 32, 64));
        float sm = 0.f;
#pragma unroll
        for (int kt = 0; kt < 13; kt++)
#pragma unroll
            for (int r = 0; r < 4; r++) {
                float p = __expf(s[kt][r] - mx);
                s[kt][r] = p; sm += p;
            }
        sm += __shfl_xor(sm, 16, 64);
        sm += __shfl_xor(sm, 32, 64);
        float rs = 1.0f / sm;
        // ---- PV with pf as a transient frag (no pf[13] array -> no spill)
        ffrag o = {0.f, 0.f, 0.f, 0.f};
#pragma unroll
        for (int kt = 0; kt < 13; kt++) {
            sfrag pf;
#pragma unroll
            for (int r = 0; r < 4; r++)
                pf[r] = (short)f2bf(s[kt][r] * rs);
            sfrag bv = *(const sfrag*)&vt_s[l16][kt * 16 + quad * 4];
            o = mfma16k16(pf, bv, o);
        }
        // D row=quad*4+r = q-local, col=l16 = d
#pragma unroll
        for (int r = 0; r < 4; r++) {
            int l = qb + quad * 4 + r;
            if (l < 200)
                Q[sbase + l * 16 + l16] = f2bf(o[r]);  // ctx in-place
        }
    }
}

// ---------------------------------------------------------------------------
// Query pooling per batch. grid 256, block 256. f32 out.
// ---------------------------------------------------------------------------
__global__ __launch_bounds__(256) void pool_k(
    const u16* __restrict__ NO, const int* __restrict__ msk,
    const float* __restrict__ qn, float* __restrict__ out)
{
    const int b = blockIdx.x;
    const int tid = threadIdx.x;
    __shared__ float q_sh[256];
    __shared__ float p_sh[256];
    __shared__ float redm[4], reds[4];

    q_sh[tid] = qn[tid];
    __syncthreads();

    float s = -1e30f;
    if (tid < 200) {
        const u16* row = NO + (size_t)(b * 200 + tid) * 256;
        float acc = 0.f;
        for (int d0 = 0; d0 < 256; d0 += 8) {
            bfrag v = *(const bfrag*)(row + d0);
#pragma unroll
            for (int j = 0; j < 8; j++) acc += bf2f((u16)v[j]) * q_sh[d0 + j];
        }
        s = acc * 0.0625f;
        if (msk[b * 200 + tid] == 0) s = -1e9f;
    }
    float m = s;
#pragma unroll
    for (int d = 1; d < 64; d <<= 1) m = fmaxf(m, __shfl_xor(m, d, 64));
    if ((tid & 63) == 0) redm[tid >> 6] = m;
    __syncthreads();
    m = fmaxf(fmaxf(redm[0], redm[1]), fmaxf(redm[2], redm[3]));
    float e = __expf(s - m);
    float sum = e;
#pragma unroll
    for (int d = 1; d < 64; d <<= 1) sum += __shfl_xor(sum, d, 64);
    if ((tid & 63) == 0) reds[tid >> 6] = sum;
    __syncthreads();
    sum = reds[0] + reds[1] + reds[2] + reds[3];
    p_sh[tid] = e / sum;
    __syncthreads();

    float acc = 0.f;
    for (int l = 0; l < 200; l++)
        acc += p_sh[l] * bf2f(NO[(size_t)(b * 200 + l) * 256 + tid]);
    out[(size_t)b * 256 + tid] = acc;
}

// ---------------------------------------------------------------------------
extern "C" void kernel_launch(void* const* d_in, const int* in_sizes, int n_in,
                              void* d_out, int out_size, void* d_ws, size_t ws_size,
                              hipStream_t stream) {
    const float* X   = (const float*)d_in[0];
    const int*   msk = (const int*)d_in[1];
    const float* Wq  = (const float*)d_in[2];
    const float* bq  = (const float*)d_in[3];
    const float* Wk  = (const float*)d_in[4];
    const float* bk  = (const float*)d_in[5];
    const float* Wv  = (const float*)d_in[6];
    const float* bv  = (const float*)d_in[7];
    const float* Wo  = (const float*)d_in[8];
    const float* bo  = (const float*)d_in[9];
    const float* qn  = (const float*)d_in[10];
    float* out = (float*)d_out;

    // ws layout (79,167,488 B):
    //   qbuf: Q head-major -> ctx in-place     26,214,400
    //   kbuf: K head-major -> news_out l-major 26,214,400
    //   vbuf: V head-major                     26,214,400
    //   wt:   [1024][256] bf16 (Wq,Wk,Wv,Wo)^T    524,288
    char* ws = (char*)d_ws;
    u16* qbuf = (u16*)(ws);
    u16* kbuf = (u16*)(ws + 26214400);
    u16* vbuf = (u16*)(ws + 52428800);
    u16* wt   = (u16*)(ws + 78643200);

    wtrans_k<<<dim3(4, 4, 4), 256, 0, stream>>>(Wq, Wk, Wv, Wo, wt);

    gemm_k<true><<<dim3(400, 6), 256, 0, stream>>>(
        X, wt, bq, bk, bv, qbuf, kbuf, vbuf);

    attn_k<<<4096, 256, 0, stream>>>(qbuf, kbuf, vbuf, msk);

    gemm_k<false><<<dim3(400, 2), 256, 0, stream>>>(
        qbuf, wt + 196608, bo, nullptr, nullptr, kbuf, nullptr, nullptr);

    pool_k<<<256, 256, 0, stream>>>(kbuf, msk, qn, out);
}

// Round 7
// 265.615 us; speedup vs baseline: 1.5353x; 1.0166x over previous
//
#include <hip/hip_runtime.h>

typedef unsigned short u16;
typedef unsigned int u32;
typedef __attribute__((ext_vector_type(8))) short bfrag;  // 8 bf16 (4 VGPRs)
typedef __attribute__((ext_vector_type(4))) short sfrag;  // 4 bf16 (2 VGPRs)
typedef __attribute__((ext_vector_type(4))) float ffrag;  // 4 fp32

// B=256, L=200, D=256, H=16, Dh=16, M=51200
// Head-major slice: [B,H,L,16], slice stride 3200 u16, b-stride 51200 u16.

__device__ __forceinline__ float bf2f(u16 u) {
    union { float f; u32 i; } c; c.i = ((u32)u) << 16; return c.f;
}
// round-half-up bf16: differs from RNE only on exact ties (1 ulp) — 2 VALU.
__device__ __forceinline__ u16 f2bf_fast(float f) {
    union { float f; u32 i; } c; c.f = f;
    return (u16)((c.i + 0x8000u) >> 16);
}
// two floats -> packed bf16x2 (lo, hi), ~5 VALU for 2 elements
__device__ __forceinline__ u32 pack2bf(float lo, float hi) {
    union { float f; u32 i; } a, b; a.f = lo; b.f = hi;
    return ((b.i + 0x8000u) & 0xFFFF0000u) | ((a.i + 0x8000u) >> 16);
}
__device__ __forceinline__ ffrag mfma16(bfrag a, bfrag b, ffrag c) {
    return __builtin_amdgcn_mfma_f32_16x16x32_bf16(a, b, c, 0, 0, 0);
}
__device__ __forceinline__ ffrag mfma16k16(sfrag a, sfrag b, ffrag c) {
    return __builtin_amdgcn_mfma_f32_16x16x16bf16_1k(a, b, c, 0, 0, 0);
}

// ---------------------------------------------------------------------------
// LDS-tiled transpose+cast: W[k][n] f32 -> Wt[n][k] bf16, 4 matrices.
// ---------------------------------------------------------------------------
__global__ __launch_bounds__(256) void wtrans_k(
    const float* __restrict__ W0, const float* __restrict__ W1,
    const float* __restrict__ W2, const float* __restrict__ W3,
    u16* __restrict__ Wt)
{
    __shared__ u16 t_s[64][72];
    const int mat = blockIdx.z;
    const float* W = (mat == 0) ? W0 : (mat == 1) ? W1 : (mat == 2) ? W2 : W3;
    const int k0 = blockIdx.x * 64, n0 = blockIdx.y * 64;
    const int r = threadIdx.x >> 2, cq = threadIdx.x & 3;

    const float* src = W + (size_t)(k0 + r) * 256 + n0 + cq * 16;
#pragma unroll
    for (int j = 0; j < 16; j += 4) {
        float4 f = *(const float4*)(src + j);
        t_s[cq * 16 + j + 0][r] = f2bf_fast(f.x);
        t_s[cq * 16 + j + 1][r] = f2bf_fast(f.y);
        t_s[cq * 16 + j + 2][r] = f2bf_fast(f.z);
        t_s[cq * 16 + j + 3][r] = f2bf_fast(f.w);
    }
    __syncthreads();
    u16* dst = Wt + ((size_t)mat * 256 + n0 + r) * 256 + k0 + cq * 16;
    *(bfrag*)(dst)     = *(const bfrag*)&t_s[r][cq * 16];
    *(bfrag*)(dst + 8) = *(const bfrag*)&t_s[r][cq * 16 + 8];
}

// ---------------------------------------------------------------------------
// GEMM: C[M,256or768] = A[M,256] @ Wt^T + bias.
// QKV=true : A = X (f32, l-major), grid (400,6), writes Q/K/V head-major bf16.
// QKV=false: A = ctx (bf16, head-major), grid (400,2), writes l-major bf16.
// Staging cvt uses pack2bf (2.5 VALU/elem vs ~5 for RNE+insert).
// ---------------------------------------------------------------------------
template<bool QKV>
__global__ __launch_bounds__(256) void gemm_k(
    const void* __restrict__ Avp, const u16* __restrict__ Wtp,
    const float* __restrict__ b0, const float* __restrict__ b1,
    const float* __restrict__ b2,
    u16* __restrict__ o0, u16* __restrict__ o1, u16* __restrict__ o2)
{
    const int m0 = blockIdx.x * 128;
    const int n0g = blockIdx.y * 128;
    const int tid = threadIdx.x;
    const int wave = tid >> 6, lane = tid & 63;
    const int quad = lane >> 4, l16 = lane & 15;
    const int wm = wave >> 1, wn = wave & 1;

    __shared__ __align__(16) u16 a_s[4][128][8];
    __shared__ __align__(16) u16 b_s[4][128][8];

    ffrag zf = {0.f, 0.f, 0.f, 0.f};
    ffrag acc[4][4];
#pragma unroll
    for (int mi = 0; mi < 4; mi++)
#pragma unroll
        for (int ni = 0; ni < 4; ni++) acc[mi][ni] = zf;

    const int sr = tid >> 2;
    const int sc = tid & 3;
    const float* Af = (const float*)Avp;
    const u16*   Ab = (const u16*)Avp;
    const u16* Wp = Wtp + (size_t)(n0g + sr) * 256 + sc * 8;

    int r0 = m0 + sr, r1 = r0 + 64;
    unsigned bA0 = (unsigned)r0 / 200u, bA1 = (unsigned)r1 / 200u;
    size_t base0 = (size_t)bA0 * 51200 + (r0 - bA0 * 200) * 16;
    size_t base1 = (size_t)bA1 * 51200 + (r1 - bA1 * 200) * 16;

    for (int kk = 0; kk < 256; kk += 32) {
        __syncthreads();
        if constexpr (QKV) {
            const float* p0 = Af + (size_t)r0 * 256 + sc * 8 + kk;
            const float* p1 = Af + (size_t)r1 * 256 + sc * 8 + kk;
            float4 f0 = *(const float4*)p0, f1 = *(const float4*)(p0 + 4);
            float4 g0 = *(const float4*)p1, g1 = *(const float4*)(p1 + 4);
            uint4 va = { pack2bf(f0.x, f0.y), pack2bf(f0.z, f0.w),
                         pack2bf(f1.x, f1.y), pack2bf(f1.z, f1.w) };
            uint4 vb = { pack2bf(g0.x, g0.y), pack2bf(g0.z, g0.w),
                         pack2bf(g1.x, g1.y), pack2bf(g1.z, g1.w) };
            *(uint4*)&a_s[sc][sr        ^ (sc << 2)][0] = va;
            *(uint4*)&a_s[sc][(sr + 64) ^ (sc << 2)][0] = vb;
        } else {
            int c = kk + sc * 8;
            size_t hofs = (size_t)(c >> 4) * 3200 + (c & 8);
            *(bfrag*)&a_s[sc][sr        ^ (sc << 2)][0] = *(const bfrag*)(Ab + base0 + hofs);
            *(bfrag*)&a_s[sc][(sr + 64) ^ (sc << 2)][0] = *(const bfrag*)(Ab + base1 + hofs);
        }
        *(bfrag*)&b_s[sc][sr        ^ (sc << 2)][0] = *(const bfrag*)(Wp + kk);
        *(bfrag*)&b_s[sc][(sr + 64) ^ (sc << 2)][0] = *(const bfrag*)(Wp + (size_t)64 * 256 + kk);
        __syncthreads();

        bfrag af[4], bfr[4];
#pragma unroll
        for (int mi = 0; mi < 4; mi++) {
            int m = wm * 64 + mi * 16 + l16;
            af[mi] = *(const bfrag*)&a_s[quad][m ^ (quad << 2)][0];
        }
#pragma unroll
        for (int ni = 0; ni < 4; ni++) {
            int n = wn * 64 + ni * 16 + l16;
            bfr[ni] = *(const bfrag*)&b_s[quad][n ^ (quad << 2)][0];
        }
#pragma unroll
        for (int mi = 0; mi < 4; mi++)
#pragma unroll
            for (int ni = 0; ni < 4; ni++)
                acc[mi][ni] = mfma16(af[mi], bfr[ni], acc[mi][ni]);
    }

    if constexpr (QKV) {
        const float* bias = (blockIdx.y < 2) ? b0 : (blockIdx.y < 4) ? b1 : b2;
        u16* dst = (blockIdx.y < 2) ? o0 : (blockIdx.y < 4) ? o1 : o2;
#pragma unroll
        for (int ni = 0; ni < 4; ni++) {
            int nloc = (blockIdx.y & 1) * 128 + wn * 64 + ni * 16 + l16;
            float bb = bias[nloc];
            size_t hbase = (size_t)(nloc >> 4) * 3200 + (nloc & 15);
#pragma unroll
            for (int mi = 0; mi < 4; mi++) {
                int rowb = m0 + wm * 64 + mi * 16 + quad * 4;
#pragma unroll
                for (int r = 0; r < 4; r++) {
                    unsigned row = rowb + r;
                    unsigned bb_ = row / 200u, ll = row - bb_ * 200u;
                    dst[(size_t)bb_ * 51200 + hbase + ll * 16] = f2bf_fast(acc[mi][ni][r] + bb);
                }
            }
        }
    } else {
#pragma unroll
        for (int ni = 0; ni < 4; ni++) {
            int col = n0g + wn * 64 + ni * 16 + l16;
            float bb = b0[col];
#pragma unroll
            for (int mi = 0; mi < 4; mi++) {
                int rowb = m0 + wm * 64 + mi * 16 + quad * 4;
#pragma unroll
                for (int r = 0; r < 4; r++)
                    o0[(size_t)(rowb + r) * 256 + col] = f2bf_fast(acc[mi][ni][r] + bb);
            }
        }
    }
}

// ---------------------------------------------------------------------------
// MHA per (b,h). grid 4096, block 256 (4 waves).
// S^T = K·Q^T (mfma 16x16x16): P lands in PV's A-operand layout, in-register.
// r7 VALU diet: hoisted K base pointers (immediate-offset loads), pack2bf
// P-cvt, normalization deferred to the o[r] write (4 muls vs 52).
// ---------------------------------------------------------------------------
__global__ __launch_bounds__(256) void attn_k(
    u16* __restrict__ Q, const u16* __restrict__ K,
    const u16* __restrict__ V, const int* __restrict__ msk)
{
    const int blk = blockIdx.x;            // b*16+h
    const int b = blk >> 4;
    const int tid = threadIdx.x;
    const int wave = tid >> 6, lane = tid & 63;
    const int quad = lane >> 4, l16 = lane & 15;
    const size_t sbase = (size_t)blk * 3200;

    __shared__ u16 vt_s[16][228];              // V^T [dh][k], pitch 228
    __shared__ __align__(16) float am_s[224];  // additive key mask (pad -1e30)

    for (int i = tid; i < 224; i += 256)
        am_s[i] = (i < 200) ? (msk[b * 200 + i] ? 0.f : -10000.f) : -1e30f;
    for (int i = tid; i < 16 * 28; i += 256)   // zero V^T pad cols 200..227
        vt_s[i / 28][200 + i % 28] = 0;
    for (int i = tid; i < 400; i += 256) {     // stage V^T
        int l = i >> 1, hf = i & 1;
        bfrag v = *(const bfrag*)(V + sbase + l * 16 + hf * 8);
#pragma unroll
        for (int j = 0; j < 8; j++) vt_s[hf * 8 + j][l] = (u16)v[j];
    }
    __syncthreads();

    // hoisted per-lane K fragment bases (row = l16, col = quad*4)
    const u16* Kb  = K + sbase + l16 * 16 + quad * 4;   // kt 0..7  (byte ofs <= 3584)
    const u16* Kb8 = Kb + 8 * 256;                      // kt 8..11 (byte ofs <= 1536)
    const u16* K12 = (l16 > 7) ? (K + sbase + 199 * 16 + quad * 4)
                               : (Kb + 12 * 256);       // kt 12, row-clamped

    for (int t = wave; t < 13; t += 4) {
        int lq = t * 16 + l16; if (lq > 199) lq = 199;  // clamp (writes guarded)
        sfrag qf = *(const sfrag*)(Q + sbase + lq * 16 + quad * 4);

        // ---- S^T tiles: lane gets S[q=l16][k=kt*16+quad*4+r], r=0..3
        float s[13][4];
#pragma unroll
        for (int kt = 0; kt < 13; kt++) {
            const u16* kp = (kt < 8) ? (Kb + kt * 256)
                          : (kt < 12) ? (Kb8 + (kt - 8) * 256) : K12;
            sfrag kf = *(const sfrag*)kp;
            ffrag c = {0.f, 0.f, 0.f, 0.f};
            c = mfma16k16(kf, qf, c);                   // D = K·Q^T tile
            ffrag am4 = *(const ffrag*)&am_s[kt * 16 + quad * 4];
#pragma unroll
            for (int r = 0; r < 4; r++) s[kt][r] = c[r] * 0.25f + am4[r];
        }
        // ---- softmax max: per-lane 52, then cross-quad (xor 16,32)
        float mx = s[0][0];
#pragma unroll
        for (int kt = 0; kt < 13; kt++)
#pragma unroll
            for (int r = 0; r < 4; r++) mx = fmaxf(mx, s[kt][r]);
        mx = fmaxf(mx, __shfl_xor(mx, 16, 64));
        mx = fmaxf(mx, __shfl_xor(mx, 32, 64));
        // ---- exp + sum + pack to bf16 P-frags (UNNORMALIZED, <=1 each)
        float sm = 0.f;
        sfrag pf[13];
#pragma unroll
        for (int kt = 0; kt < 13; kt++) {
            float p0 = __expf(s[kt][0] - mx);
            float p1 = __expf(s[kt][1] - mx);
            float p2 = __expf(s[kt][2] - mx);
            float p3 = __expf(s[kt][3] - mx);
            sm += (p0 + p1) + (p2 + p3);
            union { sfrag v; u32 u[2]; } pk;
            pk.u[0] = pack2bf(p0, p1);
            pk.u[1] = pack2bf(p2, p3);
            pf[kt] = pk.v;
        }
        sm += __shfl_xor(sm, 16, 64);
        sm += __shfl_xor(sm, 32, 64);
        float rs = 1.0f / sm;
        // ---- PV: O[q][d] = sum_k P[q][k] V[k][d]
        ffrag o = {0.f, 0.f, 0.f, 0.f};
#pragma unroll
        for (int kt = 0; kt < 13; kt++) {
            sfrag bv = *(const sfrag*)&vt_s[l16][kt * 16 + quad * 4];
            o = mfma16k16(pf[kt], bv, o);
        }
        // D row=quad*4+r = q-local, col=l16 = d; normalize at write
        int lb = t * 16 + quad * 4;
        u16* qo = Q + sbase + lb * 16 + l16;
#pragma unroll
        for (int r = 0; r < 4; r++) {
            if (lb + r < 200)
                qo[r * 16] = f2bf_fast(o[r] * rs);     // ctx in-place
        }
    }
}

// ---------------------------------------------------------------------------
// Query pooling per batch. grid 256, block 256. f32 out.
// ---------------------------------------------------------------------------
__global__ __launch_bounds__(256) void pool_k(
    const u16* __restrict__ NO, const int* __restrict__ msk,
    const float* __restrict__ qn, float* __restrict__ out)
{
    const int b = blockIdx.x;
    const int tid = threadIdx.x;
    __shared__ float q_sh[256];
    __shared__ float p_sh[256];
    __shared__ float redm[4], reds[4];

    q_sh[tid] = qn[tid];
    __syncthreads();

    float s = -1e30f;
    if (tid < 200) {
        const u16* row = NO + (size_t)(b * 200 + tid) * 256;
        float acc = 0.f;
        for (int d0 = 0; d0 < 256; d0 += 8) {
            bfrag v = *(const bfrag*)(row + d0);
#pragma unroll
            for (int j = 0; j < 8; j++) acc += bf2f((u16)v[j]) * q_sh[d0 + j];
        }
        s = acc * 0.0625f;
        if (msk[b * 200 + tid] == 0) s = -1e9f;
    }
    float m = s;
#pragma unroll
    for (int d = 1; d < 64; d <<= 1) m = fmaxf(m, __shfl_xor(m, d, 64));
    if ((tid & 63) == 0) redm[tid >> 6] = m;
    __syncthreads();
    m = fmaxf(fmaxf(redm[0], redm[1]), fmaxf(redm[2], redm[3]));
    float e = __expf(s - m);
    float sum = e;
#pragma unroll
    for (int d = 1; d < 64; d <<= 1) sum += __shfl_xor(sum, d, 64);
    if ((tid & 63) == 0) reds[tid >> 6] = sum;
    __syncthreads();
    sum = reds[0] + reds[1] + reds[2] + reds[3];
    p_sh[tid] = e / sum;
    __syncthreads();

    float acc = 0.f;
    for (int l = 0; l < 200; l++)
        acc += p_sh[l] * bf2f(NO[(size_t)(b * 200 + l) * 256 + tid]);
    out[(size_t)b * 256 + tid] = acc;
}

// ---------------------------------------------------------------------------
extern "C" void kernel_launch(void* const* d_in, const int* in_sizes, int n_in,
                              void* d_out, int out_size, void* d_ws, size_t ws_size,
                              hipStream_t stream) {
    const float* X   = (const float*)d_in[0];
    const int*   msk = (const int*)d_in[1];
    const float* Wq  = (const float*)d_in[2];
    const float* bq  = (const float*)d_in[3];
    const float* Wk  = (const float*)d_in[4];
    const float* bk  = (const float*)d_in[5];
    const float* Wv  = (const float*)d_in[6];
    const float* bv  = (const float*)d_in[7];
    const float* Wo  = (const float*)d_in[8];
    const float* bo  = (const float*)d_in[9];
    const float* qn  = (const float*)d_in[10];
    float* out = (float*)d_out;

    // ws layout (79,167,488 B):
    //   qbuf: Q head-major -> ctx in-place     26,214,400
    //   kbuf: K head-major -> news_out l-major 26,214,400
    //   vbuf: V head-major                     26,214,400
    //   wt:   [1024][256] bf16 (Wq,Wk,Wv,Wo)^T    524,288
    char* ws = (char*)d_ws;
    u16* qbuf = (u16*)(ws);
    u16* kbuf = (u16*)(ws + 26214400);
    u16* vbuf = (u16*)(ws + 52428800);
    u16* wt   = (u16*)(ws + 78643200);

    wtrans_k<<<dim3(4, 4, 4), 256, 0, stream>>>(Wq, Wk, Wv, Wo, wt);

    gemm_k<true><<<dim3(400, 6), 256, 0, stream>>>(
        X, wt, bq, bk, bv, qbuf, kbuf, vbuf);

    attn_k<<<4096, 256, 0, stream>>>(qbuf, kbuf, vbuf, msk);

    gemm_k<false><<<dim3(400, 2), 256, 0, stream>>>(
        qbuf, wt + 196608, bo, nullptr, nullptr, kbuf, nullptr, nullptr);

    pool_k<<<256, 256, 0, stream>>>(kbuf, msk, qn, out);
}